// Round 4
// baseline (1260.240 us; speedup 1.0000x reference)
//
#include <hip/hip_runtime.h>

namespace {

constexpr int H = 1024;
constexpr int W = 1024;
constexpr int PLANE = H * W;
constexpr int CIN = 18;     // total input channels
constexpr int C = 8;        // filterable channels
constexpr int TX = 16;
constexpr int TY = 16;
constexpr int PX = 2;       // pixels per thread (x-direction)
constexpr int TW = TX * PX; // 32 tile width in pixels
constexpr int SW = TW + 6;  // 38 halo width
constexpr int SH = TY + 6;  // 22 halo height
constexpr int NPOS = SW * SH;  // 836 positions
constexpr float LOG2E = 1.44269504088896340736f;

typedef _Float16 half2_t __attribute__((ext_vector_type(2)));
typedef _Float16 half8_t __attribute__((ext_vector_type(8)));

__device__ __forceinline__ float dot2acc(half2_t a, half2_t b, float c) {
#if defined(__has_builtin)
#if __has_builtin(__builtin_amdgcn_fdot2)
    return __builtin_amdgcn_fdot2(a, b, c, false);
#else
    return fmaf((float)a[0], (float)b[0], fmaf((float)a[1], (float)b[1], c));
#endif
#else
    return fmaf((float)a[0], (float)b[0], fmaf((float)a[1], (float)b[1], c));
#endif
}

__device__ __forceinline__ float fast_exp2(float x) {
#if defined(__has_builtin)
#if __has_builtin(__builtin_amdgcn_exp2f)
    return __builtin_amdgcn_exp2f(x);
#else
    return exp2f(x);
#endif
#else
    return exp2f(x);
#endif
}

template<bool INTERIOR>
__device__ __forceinline__ void contrib(half8_t q, half8_t fc,
    half2_t rp01, half2_t rp23, half2_t rp45, half2_t rp67,
    float exey, float m,
    float& ws, float& a0, float& a1, float& a2)
{
    half8_t d = q - fc;                  // 4x v_pk_add_f16
    half8_t dd = d * d;                  // 4x v_pk_mul_f16
    float lw = exey;
    lw = dot2acc(__builtin_shufflevector(dd, dd, 0, 1), rp01, lw);
    lw = dot2acc(__builtin_shufflevector(dd, dd, 2, 3), rp23, lw);
    lw = dot2acc(__builtin_shufflevector(dd, dd, 4, 5), rp45, lw);
    lw = dot2acc(__builtin_shufflevector(dd, dd, 6, 7), rp67, lw);
    float w = fast_exp2(lw);
    if (!INTERIOR) w *= m;               // padding mask
    ws += w;
    a0 = fmaf(w, (float)q[0], a0);       // v_fma_mix_f32
    a1 = fmaf(w, (float)q[1], a1);
    a2 = fmaf(w, (float)q[2], a2);
}

template<bool INTERIOR>
__device__ __forceinline__ void run_tile(const float* __restrict__ inb,
                                         float* __restrict__ outb,
                                         half8_t* __restrict__ tile,
                                         float* __restrict__ msk,
                                         int gy0, int gx0base)
{
    const int tx = threadIdx.x, ty = threadIdx.y;
    const int tid = ty * TX + tx;

    // ---- stage: one 16B packed-f16 record per halo position ----
    for (int idx = tid; idx < NPOS; idx += TX * TY) {
        int y = idx / SW;
        int x = idx - y * SW;
        int gy = gy0 + y - 3;
        int gx = gx0base + x - 3;
        half8_t hv;
        if (INTERIOR || ((unsigned)gy < (unsigned)H && (unsigned)gx < (unsigned)W)) {
            const float* p = inb + gy * W + gx;
#pragma unroll
            for (int c = 0; c < C; ++c) hv[c] = (_Float16)p[c * PLANE];
            if (!INTERIOR) msk[idx] = 1.0f;
        } else {
#pragma unroll
            for (int c = 0; c < C; ++c) hv[c] = (_Float16)0.0f;
            msk[idx] = 0.0f;
        }
        tile[idx] = hv;
    }
    __syncthreads();

    const int gy = gy0 + ty;
    const int gx0 = gx0base + PX * tx;           // left pixel of the pair (even)
    const float* pbase = inb + gy * W + gx0;     // param loads as float2 (8B aligned)

    const half8_t* lp = tile + ty * SW + PX * tx; // window origin of px0
    const half8_t fc0 = lp[3 * SW + 3];           // centers
    const half8_t fc1 = lp[3 * SW + 4];

    // per-pixel params, log2e folded in
    half2_t rp0_01, rp0_23, rp0_45, rp0_67;
    half2_t rp1_01, rp1_23, rp1_45, rp1_67;
    {
        float r0[C], r1[C];
#pragma unroll
        for (int c = 0; c < C; ++c) {
            float2 p2 = *(const float2*)(pbase + (size_t)(C + c) * PLANE);
            r0[c] = -(p2.x * p2.x) * LOG2E;
            r1[c] = -(p2.y * p2.y) * LOG2E;
        }
        rp0_01 = half2_t{(_Float16)r0[0], (_Float16)r0[1]};
        rp0_23 = half2_t{(_Float16)r0[2], (_Float16)r0[3]};
        rp0_45 = half2_t{(_Float16)r0[4], (_Float16)r0[5]};
        rp0_67 = half2_t{(_Float16)r0[6], (_Float16)r0[7]};
        rp1_01 = half2_t{(_Float16)r1[0], (_Float16)r1[1]};
        rp1_23 = half2_t{(_Float16)r1[2], (_Float16)r1[3]};
        rp1_45 = half2_t{(_Float16)r1[4], (_Float16)r1[5]};
        rp1_67 = half2_t{(_Float16)r1[6], (_Float16)r1[7]};
    }
    float2 pxv = *(const float2*)(pbase + (size_t)16 * PLANE);
    float2 pyv = *(const float2*)(pbase + (size_t)17 * PLANE);
    const float sx0 = -(pxv.x * pxv.x) * LOG2E;
    const float sx1 = -(pxv.y * pxv.y) * LOG2E;
    const float sy0 = -(pyv.x * pyv.x) * LOG2E;
    const float sy1 = -(pyv.y * pyv.y) * LOG2E;

    float ex0[7], ex1[7];
#pragma unroll
    for (int j = 0; j < 7; ++j) {
        float j2 = (float)((j - 3) * (j - 3));
        ex0[j] = sx0 * j2;
        ex1[j] = sx1 * j2;
    }

    float ws0 = 0.f, a00 = 0.f, a01 = 0.f, a02 = 0.f;
    float ws1 = 0.f, a10 = 0.f, a11 = 0.f, a12 = 0.f;

#pragma unroll
    for (int i = 0; i < 7; ++i) {
        const float dy2 = (float)((i - 3) * (i - 3));
        const float ey0 = sy0 * dy2;
        const float ey1 = sy1 * dy2;
        const half8_t* row = lp + i * SW;
        const float* mrow = msk + (ty + i) * SW + PX * tx;
#pragma unroll
        for (int jj = 0; jj < 8; ++jj) {
            half8_t q = row[jj];                 // one ds_read_b128, shared by both px
            float m = INTERIOR ? 1.0f : mrow[jj];  // same mask elem for both uses
            if (jj < 7)  // px0, window column jj
                contrib<INTERIOR>(q, fc0, rp0_01, rp0_23, rp0_45, rp0_67,
                                  ex0[jj] + ey0, m, ws0, a00, a01, a02);
            if (jj > 0)  // px1, window column jj-1
                contrib<INTERIOR>(q, fc1, rp1_01, rp1_23, rp1_45, rp1_67,
                                  ex1[jj - 1] + ey1, m, ws1, a10, a11, a12);
        }
    }

    const float inv0 = 1.0f / ws0;
    const float inv1 = 1.0f / ws1;
    float* ob = outb + gy * W + gx0;
    *(float2*)(ob)             = float2{a00 * inv0, a10 * inv1};
    *(float2*)(ob + PLANE)     = float2{a01 * inv0, a11 * inv1};
    *(float2*)(ob + 2 * PLANE) = float2{a02 * inv0, a12 * inv1};
}

// launch_bounds (256,4): VGPR cap 128. (256,8) forced 32 VGPRs -> 800MB of
// scratch spill traffic, 397us (R3). Do not raise the min-waves bound.
__global__ __launch_bounds__(TX * TY, 4) void bilateral_kernel(const float* __restrict__ in,
                                                               float* __restrict__ out)
{
    __shared__ __align__(16) half8_t tile[NPOS];
    __shared__ float msk[NPOS];
    const int b = blockIdx.z;
    const int gx0base = blockIdx.x * TW;
    const int gy0 = blockIdx.y * TY;
    const float* inb = in + (size_t)b * CIN * PLANE;
    float* outb = out + (size_t)b * 3 * PLANE;

    const bool interior = (gx0base >= 3) && (gx0base + TW + 3 <= W) &&
                          (gy0 >= 3) && (gy0 + TY + 3 <= H);
    if (interior)
        run_tile<true>(inb, outb, tile, msk, gy0, gx0base);
    else
        run_tile<false>(inb, outb, tile, msk, gy0, gx0base);
}

} // namespace

extern "C" void kernel_launch(void* const* d_in, const int* in_sizes, int n_in,
                              void* d_out, int out_size, void* d_ws, size_t ws_size,
                              hipStream_t stream)
{
    const float* in = (const float*)d_in[0];
    float* out = (float*)d_out;
    dim3 grid(W / TW, H / TY, 2);
    dim3 block(TX, TY);
    hipLaunchKernelGGL(bilateral_kernel, grid, block, 0, stream, in, out);
}

// Round 5
// 253.810 us; speedup vs baseline: 4.9653x; 4.9653x over previous
//
#include <hip/hip_runtime.h>

namespace {

constexpr int H = 1024;
constexpr int W = 1024;
constexpr int PLANE = H * W;
constexpr int CIN = 18;     // total input channels
constexpr int C = 8;        // filterable channels
constexpr int TX = 16;
constexpr int TY = 16;
constexpr int SW = TX + 6;  // 22 halo tile width
constexpr int SH = TY + 6;  // 22 halo tile height
constexpr int NPOS = SW * SH;  // 484 positions
constexpr float LOG2E = 1.44269504088896340736f;

typedef _Float16 half2_t __attribute__((ext_vector_type(2)));
typedef _Float16 half8_t __attribute__((ext_vector_type(8)));

__device__ __forceinline__ float dot2acc(half2_t a, half2_t b, float c) {
#if defined(__has_builtin)
#if __has_builtin(__builtin_amdgcn_fdot2)
    return __builtin_amdgcn_fdot2(a, b, c, false);
#else
    return fmaf((float)a[0], (float)b[0], fmaf((float)a[1], (float)b[1], c));
#endif
#else
    return fmaf((float)a[0], (float)b[0], fmaf((float)a[1], (float)b[1], c));
#endif
}

__device__ __forceinline__ float fast_exp2(float x) {
#if defined(__has_builtin)
#if __has_builtin(__builtin_amdgcn_exp2f)
    return __builtin_amdgcn_exp2f(x);
#else
    return exp2f(x);
#endif
#else
    return exp2f(x);
#endif
}

template<bool INTERIOR>
__device__ __forceinline__ void run_tile(const float* __restrict__ inb,
                                         float* __restrict__ outb,
                                         half8_t* __restrict__ tile,
                                         float* __restrict__ msk,
                                         int gy0, int gx0)
{
    const int tx = threadIdx.x, ty = threadIdx.y;
    const int tid = ty * TX + tx;

    const int gy = gy0 + ty, gx = gx0 + tx;
    const int pofs = gy * W + gx;

    // ---- per-pixel params FIRST (before the barrier) so their global
    // latency overlaps the staging loop + barrier wait. log2e folded in.
    half2_t rp01, rp23, rp45, rp67, rps;
    {
        const float* pp = inb + (size_t)C * PLANE + pofs;
        float r[C];
#pragma unroll
        for (int c = 0; c < C; ++c) {
            float p = pp[(size_t)c * PLANE];
            r[c] = -(p * p) * LOG2E;
        }
        float px_ = pp[(size_t)8 * PLANE];
        float py_ = pp[(size_t)9 * PLANE];
        rp01 = half2_t{(_Float16)r[0], (_Float16)r[1]};
        rp23 = half2_t{(_Float16)r[2], (_Float16)r[3]};
        rp45 = half2_t{(_Float16)r[4], (_Float16)r[5]};
        rp67 = half2_t{(_Float16)r[6], (_Float16)r[7]};
        rps  = half2_t{(_Float16)(-(px_ * px_) * LOG2E),
                       (_Float16)(-(py_ * py_) * LOG2E)};
    }

    // ---- stage: one 16B packed-f16 record per halo position ----
    for (int idx = tid; idx < NPOS; idx += TX * TY) {
        int y = idx / SW;
        int x = idx - y * SW;
        int sy_ = gy0 + y - 3;
        int sx_ = gx0 + x - 3;
        half8_t hv;
        if (INTERIOR || ((unsigned)sy_ < (unsigned)H && (unsigned)sx_ < (unsigned)W)) {
            const float* p = inb + sy_ * W + sx_;
#pragma unroll
            for (int c = 0; c < C; ++c) hv[c] = (_Float16)p[(size_t)c * PLANE];
            if (!INTERIOR) msk[idx] = 1.0f;
        } else {
#pragma unroll
            for (int c = 0; c < C; ++c) hv[c] = (_Float16)0.0f;
            msk[idx] = 0.0f;
        }
        tile[idx] = hv;
    }
    __syncthreads();

    const half8_t* lp = tile + ty * SW + tx;  // window origin for this pixel
    const half8_t fc = lp[3 * SW + 3];        // center (f16, so d==0 exactly)

    float acc0 = 0.f, acc1 = 0.f, acc2 = 0.f, ws = 0.f;
#pragma unroll
    for (int i = 0; i < 7; ++i) {
        const half8_t* row = lp + i * SW;
        const float* mrow = msk + (ty + i) * SW + tx;
#pragma unroll
        for (int j = 0; j < 7; ++j) {
            half8_t q = row[j];                 // one ds_read_b128
            half8_t d = q - fc;                 // 4x v_pk_add_f16
            half8_t dd = d * d;                 // 4x v_pk_mul_f16
            // spatial term as a 5th dot2 against compile-time {dx^2, dy^2}
            const half2_t cst = half2_t{(_Float16)(float)((j - 3) * (j - 3)),
                                        (_Float16)(float)((i - 3) * (i - 3))};
            float lw = dot2acc(cst, rps, 0.0f);
            lw = dot2acc(__builtin_shufflevector(dd, dd, 0, 1), rp01, lw);
            lw = dot2acc(__builtin_shufflevector(dd, dd, 2, 3), rp23, lw);
            lw = dot2acc(__builtin_shufflevector(dd, dd, 4, 5), rp45, lw);
            lw = dot2acc(__builtin_shufflevector(dd, dd, 6, 7), rp67, lw);
            float w = fast_exp2(lw);
            if (!INTERIOR) w *= mrow[j];        // padding mask
            ws += w;
            acc0 = fmaf(w, (float)q[0], acc0);  // v_fma_mix_f32
            acc1 = fmaf(w, (float)q[1], acc1);
            acc2 = fmaf(w, (float)q[2], acc2);
        }
    }
    const float inv = 1.0f / ws;
    outb[pofs]             = acc0 * inv;
    outb[PLANE + pofs]     = acc1 * inv;
    outb[2 * PLANE + pofs] = acc2 * inv;
}

// launch_bounds (256,4): VGPR cap 128; R2 used 56 with this shape.
// (256,8) forced 32 VGPRs -> 800MB scratch spill, 397us (R3). 2px/thread
// fully unrolled -> 1.7GB spill, 1117us (R4). Keep this shape.
__global__ __launch_bounds__(TX * TY, 4) void bilateral_kernel(const float* __restrict__ in,
                                                               float* __restrict__ out)
{
    __shared__ __align__(16) half8_t tile[NPOS];
    __shared__ float msk[NPOS];
    const int b = blockIdx.z;
    const int gx0 = blockIdx.x * TX;
    const int gy0 = blockIdx.y * TY;
    const float* inb = in + (size_t)b * CIN * PLANE;
    float* outb = out + (size_t)b * 3 * PLANE;

    const bool interior = (gx0 >= 3) && (gx0 + TX + 3 <= W) &&
                          (gy0 >= 3) && (gy0 + TY + 3 <= H);
    if (interior)
        run_tile<true>(inb, outb, tile, msk, gy0, gx0);
    else
        run_tile<false>(inb, outb, tile, msk, gy0, gx0);
}

} // namespace

extern "C" void kernel_launch(void* const* d_in, const int* in_sizes, int n_in,
                              void* d_out, int out_size, void* d_ws, size_t ws_size,
                              hipStream_t stream)
{
    const float* in = (const float*)d_in[0];
    float* out = (float*)d_out;
    dim3 grid(W / TX, H / TY, 2);
    dim3 block(TX, TY);
    hipLaunchKernelGGL(bilateral_kernel, grid, block, 0, stream, in, out);
}